// Round 17
// baseline (572.218 us; speedup 1.0000x reference)
//
#include <hip/hip_runtime.h>
#include <math.h>

#define DIN 640
#define DH 1024
#define DOUT 128
#define CODEDIM 256
#define NE 8
#define NB 8
#define NT 1024
#define NTOK 8192
#define TAU_INV 10.0f
#define FEPS 1e-8f

// out layout: full_output[8*1024*1024], aux[1], div[1], ent[8], mean[8], std[8]
#define AUX_OFF  8388608
#define DIV_OFF  8388609
#define ENT_OFF  8388610
#define MEAN_OFF 8388618
#define STD_OFF  8388626

typedef __bf16 bf16;
typedef bf16 bf16x8 __attribute__((ext_vector_type(8)));
typedef float f32x4 __attribute__((ext_vector_type(4)));

__device__ __forceinline__ float gelu(float x) {
  return 0.5f * x * (1.0f + erff(x * 0.70710678118654752f));
}

#define BAR() do { asm volatile("" ::: "memory"); __builtin_amdgcn_s_barrier(); asm volatile("" ::: "memory"); } while(0)
#define VMCNT6 asm volatile("s_waitcnt vmcnt(6)" ::: "memory")
#define VMCNT0 asm volatile("s_waitcnt vmcnt(0)" ::: "memory")

// async global->LDS, 16B/lane; LDS dest is wave-uniform base (HW adds lane*16);
// global source IS per-lane (pre-swizzled-global pattern, r5/r11/r12-proven).
__device__ __forceinline__ void gload16(const void* g, void* l) {
  __builtin_amdgcn_global_load_lds(
      (const __attribute__((address_space(1))) unsigned int*)g,
      (__attribute__((address_space(3))) unsigned int*)l, 16, 0, 0);
}

// ---------------- block reduction helpers (blockDim multiple of 64) ----------
__device__ __forceinline__ float blk_sum(float v, float* sb) {
  #pragma unroll
  for (int o = 32; o > 0; o >>= 1) v += __shfl_down(v, o, 64);
  __syncthreads();
  if ((threadIdx.x & 63) == 0) sb[threadIdx.x >> 6] = v;
  __syncthreads();
  float tot = 0.f;
  int nw = blockDim.x >> 6;
  for (int i = 0; i < nw; ++i) tot += sb[i];
  return tot;
}

__device__ __forceinline__ float blk_max(float v, float* sb) {
  #pragma unroll
  for (int o = 32; o > 0; o >>= 1) v = fmaxf(v, __shfl_down(v, o, 64));
  __syncthreads();
  if ((threadIdx.x & 63) == 0) sb[threadIdx.x >> 6] = v;
  __syncthreads();
  float m = -3.0e38f;
  int nw = blockDim.x >> 6;
  for (int i = 0; i < nw; ++i) m = fmaxf(m, sb[i]);
  return m;
}

// ================== fused prep: 6 roles in one launch (r13-proven) ===========
__global__ __launch_bounds__(256)
void k_prep(const float* __restrict__ h, const float* __restrict__ ce,
            const float* __restrict__ gn, const float* __restrict__ ca,
            const float* __restrict__ fi, const float* __restrict__ W1,
            const float* __restrict__ W2,
            bf16* __restrict__ w1t, bf16* __restrict__ w2t,
            bf16* __restrict__ xb, float* __restrict__ ew,
            float* __restrict__ out) {
  const int bid = blockIdx.x;
  const int tid = threadIdx.x;
  if (bid < 1280) {
    // ---- role A: W1[e][640][1024] -> w1t[e][1024][640]*imp, imp inline ----
    __shared__ float tile[64][65];
    __shared__ float sb[8];
    __shared__ float red[2];
    int c0 = (bid & 15) * 64;
    int r0 = ((bid >> 4) % 10) * 64;
    int ee = bid / 160;
    const float* s = W1 + (size_t)ee*DIN*DH;
    bf16* d = w1t + (size_t)ee*DH*DIN;
    int i2v = tid + 512;
    float v0 = fi[ee*DIN + tid] * 2.0f;
    float v1 = fi[ee*DIN + tid + 256] * 2.0f;
    float v2 = (i2v < DIN) ? fi[ee*DIN + i2v] * 2.0f : -3.0e38f;
    float m = blk_max(fmaxf(v0, fmaxf(v1, v2)), sb);
    float se = expf(v0 - m) + expf(v1 - m) + ((i2v < DIN) ? expf(v2 - m) : 0.f);
    float ssum = blk_sum(se, sb);
    if (tid == 0) { red[0] = m; red[1] = 1.0f / ssum; }
    int tx = tid & 63, ty = tid >> 6;
    #pragma unroll
    for (int p = 0; p < 16; ++p) {
      int r = p*4 + ty;
      tile[r][tx] = s[(size_t)(r0 + r)*DH + c0 + tx];
    }
    __syncthreads();
    float sc = expf(fi[ee*DIN + r0 + tx]*2.0f - red[0]) * red[1];
    #pragma unroll
    for (int p = 0; p < 16; ++p) {
      int cr = p*4 + ty;
      d[(size_t)(c0 + cr)*DIN + r0 + tx] = (bf16)(tile[tx][cr] * sc);
    }
  } else if (bid < 1536) {
    // ---- role B: W2[e][1024][128] -> w2t[e][128][1024] ----
    __shared__ float tile[64][65];
    int c = bid - 1280;
    int c0 = (c & 1) * 64;
    int r0 = ((c >> 1) & 15) * 64;
    int ee = c >> 5;
    const float* s = W2 + (size_t)ee*DH*DOUT;
    bf16* d = w2t + (size_t)ee*DOUT*DH;
    int tx = tid & 63, ty = tid >> 6;
    #pragma unroll
    for (int p = 0; p < 16; ++p) {
      int r = p*4 + ty;
      tile[r][tx] = s[(size_t)(r0 + r)*DOUT + c0 + tx];
    }
    __syncthreads();
    #pragma unroll
    for (int p = 0; p < 16; ++p) {
      int cr = p*4 + ty;
      d[(size_t)(c0 + cr)*DH + r0 + tx] = (bf16)tile[tx][cr];
    }
  } else if (bid < 4096) {
    // ---- role C: h f32 -> bf16 ----
    size_t i = (size_t)(bid - 1536)*256 + tid;
    const float4* p = (const float4*)(h + i*8);
    float4 u0 = p[0], u1 = p[1];
    bf16x8 o;
    o[0]=(bf16)u0.x; o[1]=(bf16)u0.y; o[2]=(bf16)u0.z; o[3]=(bf16)u0.w;
    o[4]=(bf16)u1.x; o[5]=(bf16)u1.y; o[6]=(bf16)u1.z; o[7]=(bf16)u1.w;
    *(bf16x8*)(xb + i*8) = o;
  } else if (bid < 6144) {
    // ---- role D: router, anchors normalized inline ----
    __shared__ float anc[NE*CODEDIM];
    __shared__ float sd[256];
    __shared__ float invn[8];
    int c = bid - 4096;
    for (int i = tid; i < NE*CODEDIM; i += 256) anc[i] = ca[i];
    __syncthreads();
    {
      int e8 = tid >> 5, base = e8*CODEDIM + (tid & 31)*8;
      float ps = 0.f;
      #pragma unroll
      for (int j = 0; j < 8; ++j) { float v = anc[base + j]; ps += v*v; }
      sd[tid] = ps;
    }
    __syncthreads();
    if (tid < 8) {
      float s2 = 0.f;
      for (int j = 0; j < 32; ++j) s2 += sd[tid*32 + j];
      invn[tid] = 1.0f / fmaxf(sqrtf(s2), 1e-12f);
    }
    __syncthreads();
    int wv = tid >> 6, lane = tid & 63;
    int token = c*4 + wv;
    float4 x = *(const float4*)(ce + (size_t)token*CODEDIM + lane*4);
    float ss = x.x*x.x + x.y*x.y + x.z*x.z + x.w*x.w;
    #pragma unroll
    for (int o = 1; o < 64; o <<= 1) ss += __shfl_xor(ss, o, 64);
    float invx = 1.0f / fmaxf(sqrtf(ss), 1e-12f);
    const float* g = gn + (size_t)token*NE;
    float z[8];
    float m = -3.0e38f;
    #pragma unroll
    for (int e2 = 0; e2 < NE; ++e2) {
      const float* a = anc + e2*CODEDIM + lane*4;
      float d = x.x*a[0] + x.y*a[1] + x.z*a[2] + x.w*a[3];
      #pragma unroll
      for (int o = 1; o < 64; o <<= 1) d += __shfl_xor(d, o, 64);
      z[e2] = (d * invx * invn[e2] + g[e2]) * TAU_INV;
      m = fmaxf(m, z[e2]);
    }
    float ssum = 0.f;
    float pz[8];
    #pragma unroll
    for (int e2 = 0; e2 < NE; ++e2) { pz[e2] = expf(z[e2] - m); ssum += pz[e2]; }
    float num = 0.f;
    #pragma unroll
    for (int e2 = 0; e2 < NE; ++e2) num = (lane == e2) ? pz[e2] : num;
    if (lane < NE) ew[(size_t)token*NE + lane] = num / ssum;
  } else if (bid < 6152) {
    // ---- role E: importance stats (ENT/MEAN/STD) ----
    __shared__ float sb[8];
    int e = bid - 6144;
    int d2v = tid + 512;
    float v0 = fi[e*DIN + tid] * 2.0f;
    float v1 = fi[e*DIN + tid + 256] * 2.0f;
    float v2 = (d2v < DIN) ? fi[e*DIN + d2v] * 2.0f : -3.0e38f;
    float m = blk_max(fmaxf(v0, fmaxf(v1, v2)), sb);
    float e0 = expf(v0 - m), e1 = expf(v1 - m);
    float e2 = (d2v < DIN) ? expf(v2 - m) : 0.f;
    float s = blk_sum(e0 + e1 + e2, sb);
    float inv = 1.0f / s;
    float p0 = e0*inv, p1 = e1*inv, p2 = e2*inv;
    float ok2 = (d2v < DIN) ? 1.f : 0.f;
    float sp  = p0 + p1 + ok2*p2;
    float sp2 = p0*p0 + p1*p1 + ok2*p2*p2;
    float sent = p0*logf(p0 + FEPS) + p1*logf(p1 + FEPS) + ok2*p2*logf(p2 + FEPS);
    sp   = blk_sum(sp, sb);
    sp2  = blk_sum(sp2, sb);
    sent = blk_sum(sent, sb);
    if (tid == 0) {
      out[ENT_OFF + e]  = -sent;
      out[MEAN_OFF + e] = sp * (1.0f/DIN);
      float var = (sp2 - sp*sp*(1.0f/DIN)) * (1.0f/(DIN-1));
      out[STD_OFF + e]  = sqrtf(fmaxf(var, 0.f));
    }
  } else {
    // ---- role F: diversity loss ----
    __shared__ float sd[256];
    int p = tid >> 2, q = tid & 3;
    int i = p >> 3, j = p & 7;
    float dot = 0.f;
    for (int d = q*160; d < q*160 + 160; ++d) dot += fi[i*DIN + d] * fi[j*DIN + d];
    sd[tid] = dot;
    __syncthreads();
    if (tid < 64) {
      float s = sd[tid*4] + sd[tid*4+1] + sd[tid*4+2] + sd[tid*4+3];
      int ii = tid >> 3, jj = tid & 7;
      float val = (ii != jj) ? s*s : 0.f;
      #pragma unroll
      for (int o = 32; o > 0; o >>= 1) val += __shfl_down(val, o, 64);
      if (tid == 0) out[DIV_OFF] = val * (1.0f/56.0f);
    }
  }
}

// ================== GEMM1: H = gelu(X @ W1 + b1), bf16 out ===================
// r12's proven per-wave schedule, widened to 128(M)x256(N) with 512 threads =
// 8 waves (2Mx4N, each wave the identical 64x64 / acc[4][4] / 32-MFMA step).
// LDS 48KB single-buffered (A 16K + B 32K) -> 3 blocks/CU = 24 waves/CU
// (2x r12's 12) — cross-block overlap is the proven mechanism (r14/r15 lost
// it; this doubles it). Swizzle slot^row&7 on 128B rows; inverse-swizzled
// per-lane global src + linear gload dest (T21). Epilogue overlays in two
// 128-col passes (272B rows, r12's verified store path).
#define G1_LDS 49152
__global__ __launch_bounds__(512, 6)
void k_g1(const bf16* __restrict__ xb, const bf16* __restrict__ w1t,
          const float* __restrict__ b1, bf16* __restrict__ Hb, int ebase) {
  __shared__ __align__(16) char L[G1_LDS];   // A [0,16K), B [16K,48K); overlay 128x272
  const int bid = blockIdx.x;
  const int el = bid & 3, e = ebase + el;
  const int nt = (bid >> 2) & 3, mt = bid >> 4;
  const int M0 = mt * 128, N0 = nt * 256;
  const int tid = threadIdx.x;
  const int lane = tid & 63, w = tid >> 6;
  const int l15 = lane & 15, g4 = lane >> 4;
  const int wr = w >> 2, wc = w & 3;          // 2M x 4N wave grid; 64x64 each

  // staging sources (per-lane, inverse-swizzled; involution on slot bits 4-6)
  const char* gAsrc[2];
  #pragma unroll
  for (int j = 0; j < 2; ++j) {
    unsigned p = (unsigned)((w*2 + j)*1024 + lane*16);
    unsigned q = p ^ (((p >> 7) & 7u) << 4);
    gAsrc[j] = (const char*)xb + (size_t)(M0 + (int)(q >> 7))*(DIN*2) + (q & 127u);
  }
  const char* gBsrc[4];
  #pragma unroll
  for (int j = 0; j < 4; ++j) {
    unsigned p = (unsigned)((w*4 + j)*1024 + lane*16);
    unsigned q = p ^ (((p >> 7) & 7u) << 4);
    gBsrc[j] = (const char*)w1t + (size_t)(e*DH + N0 + (int)(q >> 7))*(DIN*2) + (q & 127u);
  }

  unsigned afOff[4][2], bfOff[4][2];
  #pragma unroll
  for (int mi = 0; mi < 4; ++mi)
    #pragma unroll
    for (int kk = 0; kk < 2; ++kk) {
      int row = wr*64 + mi*16 + l15;
      int slot = kk*4 + g4;
      afOff[mi][kk] = (unsigned)(row*128 + ((slot ^ (row & 7)) << 4));
    }
  #pragma unroll
  for (int ni = 0; ni < 4; ++ni)
    #pragma unroll
    for (int kk = 0; kk < 2; ++kk) {
      int row = wc*64 + ni*16 + l15;
      int slot = kk*4 + g4;
      bfOff[ni][kk] = (unsigned)(16384 + row*128 + ((slot ^ (row & 7)) << 4));
    }

  f32x4 acc[4][4] = {};
  for (int t = 0; t < 10; ++t) {
    if (t) BAR();                    // all reads of tile t-1 done before restage
    size_t ko = (size_t)t * 128;
    #pragma unroll
    for (int j = 0; j < 2; ++j)
      gload16(gAsrc[j] + ko, L + (w*2 + j)*1024);
    #pragma unroll
    for (int j = 0; j < 4; ++j)
      gload16(gBsrc[j] + ko, L + 16384 + (w*4 + j)*1024);
    VMCNT0;
    BAR();
    #pragma unroll
    for (int kk = 0; kk < 2; ++kk) {
      bf16x8 af[4], bfr[4];
      #pragma unroll
      for (int mi = 0; mi < 4; ++mi) af[mi] = *(const bf16x8*)(L + afOff[mi][kk]);
      #pragma unroll
      for (int ni = 0; ni < 4; ++ni) bfr[ni] = *(const bf16x8*)(L + bfOff[ni][kk]);
      #pragma unroll
      for (int mi = 0; mi < 4; ++mi)
        #pragma unroll
        for (int ni = 0; ni < 4; ++ni)
          acc[mi][ni] = __builtin_amdgcn_mfma_f32_16x16x32_bf16(
              af[mi], bfr[ni], acc[mi][ni], 0, 0, 0);
    }
  }
  BAR();
  // epilogue: +b1, exact GELU; two 128-col passes through a 128x272B overlay
  float b1v[4];
  #pragma unroll
  for (int ni = 0; ni < 4; ++ni)
    b1v[ni] = b1[e*DH + N0 + wc*64 + ni*16 + l15];
  #pragma unroll
  for (int hp = 0; hp < 2; ++hp) {
    if ((wc >> 1) == hp) {
      int colL = (wc & 1)*64;                 // col within this 128-col half
      #pragma unroll
      for (int mi = 0; mi < 4; ++mi)
        #pragma unroll
        for (int ni = 0; ni < 4; ++ni)
          #pragma unroll
          for (int r = 0; r < 4; ++r) {
            float v = gelu(acc[mi][ni][r] + b1v[ni]);  // C/D: row=(l>>4)*4+r, col=l&15
            int row = wr*64 + mi*16 + g4*4 + r;
            int col = colL + ni*16 + l15;
            *(bf16*)(L + row*272 + col*2) = (bf16)v;
          }
    }
    __syncthreads();
    #pragma unroll
    for (int j = 0; j < 4; ++j) {
      int c = j*512 + tid;
      int row = c >> 4, slot = c & 15;        // 128 rows x 16 slots of 16B
      bf16x8 v = *(const bf16x8*)(L + row*272 + slot*16);
      *(bf16x8*)((char*)Hb + (size_t)(el*NTOK + M0 + row)*(DH*2)
                 + (size_t)(N0 + hp*128)*2 + slot*16) = v;
    }
    if (hp == 0) __syncthreads();             // half-0 reads done before overwrite
  }
}

// ================== GEMM2: out = (H @ W2 + b2) * gate, f32 ===================
// r11-proven (FROZEN): 64x128 tile, BK=64, dbuf, counted vmcnt(6).
__global__ __launch_bounds__(256, 3)
void k_g2(const bf16* __restrict__ Hb, const bf16* __restrict__ w2t,
          const float* __restrict__ b2, const float* __restrict__ ew,
          float* __restrict__ out, int ebase) {
  __shared__ __align__(16) char L[49152];
  const int bid = blockIdx.x;
  const int el = bid & 3, e = ebase + el;
  const int mt = bid >> 2;
  const int M0 = mt * 64;
  const int tid = threadIdx.x;
  const int lane = tid & 63, w = tid >> 6;
  const int l15 = lane & 15, g4 = lane >> 4;
  const int nb = w * 32;

  const char* gAsrc[2];
  #pragma unroll
  for (int j = 0; j < 2; ++j) {
    unsigned p = (unsigned)((w*2 + j)*1024 + lane*16);
    unsigned q = p ^ (((p >> 7) & 7u) << 4);
    gAsrc[j] = (const char*)Hb + (size_t)(el*NTOK + M0 + (int)(q >> 7))*(DH*2) + (q & 127u);
  }
  const char* gBsrc[4];
  #pragma unroll
  for (int j = 0; j < 4; ++j) {
    unsigned p = (unsigned)((w*4 + j)*1024 + lane*16);
    unsigned q = p ^ (((p >> 7) & 7u) << 4);
    gBsrc[j] = (const char*)w2t + (size_t)(e*DOUT + (int)(q >> 7))*(DH*2) + (q & 127u);
  }
  auto STAGE = [&](int buf, int t) {
    size_t ko = (size_t)t * 128;
    #pragma unroll
    for (int j = 0; j < 2; ++j)
      gload16(gAsrc[j] + ko, L + buf*8192 + (w*2 + j)*1024);
    #pragma unroll
    for (int j = 0; j < 4; ++j)
      gload16(gBsrc[j] + ko, L + 16384 + buf*16384 + (w*4 + j)*1024);
  };

  unsigned afOff[4][2], bfOff[2][2];
  #pragma unroll
  for (int mi = 0; mi < 4; ++mi)
    #pragma unroll
    for (int kk = 0; kk < 2; ++kk) {
      int row = mi*16 + l15;
      int slot = kk*4 + g4;
      afOff[mi][kk] = (unsigned)(row*128 + ((slot ^ (row & 7)) << 4));
    }
  #pragma unroll
  for (int ni = 0; ni < 2; ++ni)
    #pragma unroll
    for (int kk = 0; kk < 2; ++kk) {
      int row = nb + ni*16 + l15;
      int slot = kk*4 + g4;
      bfOff[ni][kk] = (unsigned)(row*128 + ((slot ^ (row & 7)) << 4));
    }

  f32x4 acc[4][2] = {};
  STAGE(0, 0);
  for (int t = 0; t < 16; ++t) {
    int buf = t & 1;
    if (t < 15) { STAGE(buf ^ 1, t + 1); VMCNT6; } else { VMCNT0; }
    BAR();
    const char* Ab = L + buf*8192;
    const char* Bb = L + 16384 + buf*16384;
    #pragma unroll
    for (int kk = 0; kk < 2; ++kk) {
      bf16x8 af[4], bfr[2];
      #pragma unroll
      for (int mi = 0; mi < 4; ++mi) af[mi] = *(const bf16x8*)(Ab + afOff[mi][kk]);
      #pragma unroll
      for (int ni = 0; ni < 2; ++ni) bfr[ni] = *(const bf16x8*)(Bb + bfOff[ni][kk]);
      #pragma unroll
      for (int mi = 0; mi < 4; ++mi)
        #pragma unroll
        for (int ni = 0; ni < 2; ++ni)
          acc[mi][ni] = __builtin_amdgcn_mfma_f32_16x16x32_bf16(
              af[mi], bfr[ni], acc[mi][ni], 0, 0, 0);
    }
    BAR();
  }
  float b2v[2];
  #pragma unroll
  for (int ni = 0; ni < 2; ++ni)
    b2v[ni] = b2[e*DOUT + nb + ni*16 + l15];
  float gt[4][4];
  #pragma unroll
  for (int mi = 0; mi < 4; ++mi)
    #pragma unroll
    for (int r = 0; r < 4; ++r)
      gt[mi][r] = ew[(size_t)(M0 + mi*16 + g4*4 + r)*NE + e];
  #pragma unroll
  for (int mi = 0; mi < 4; ++mi)
    #pragma unroll
    for (int ni = 0; ni < 2; ++ni)
      #pragma unroll
      for (int r = 0; r < 4; ++r) {
        int tok = M0 + mi*16 + g4*4 + r;
        int o = nb + ni*16 + l15;
        out[(size_t)tok*(NE*DOUT) + e*DOUT + o] = (acc[mi][ni][r] + b2v[ni]) * gt[mi][r];
      }
}

// ========== tail: expert counts + routing aux loss in ONE launch =============
__global__ __launch_bounds__(1024)
void k_tail(const float* __restrict__ ew, float* __restrict__ out) {
  __shared__ float sb[16];
  int tid = threadIdx.x;
  float c[8];
  float tot = 0.f;
  #pragma unroll
  for (int j = 0; j < 8; ++j) {
    int g = j*1024 + tid;
    float s = 0.f;
    #pragma unroll
    for (int b = 0; b < NB; ++b) s += ew[b*(NT*NE) + g];
    c[j] = s;
    tot += s;
  }
  float total = blk_sum(tot, sb);
  float invt = 1.0f / (total + FEPS);
  float sq = 0.f, ent = 0.f;
  #pragma unroll
  for (int j = 0; j < 8; ++j) {
    sq += c[j]*c[j];
    float ld = c[j] * invt;
    ent -= ld * logf(ld + FEPS);
  }
  sq = blk_sum(sq, sb);
  ent = blk_sum(ent, sb);
  if (tid == 0) {
    float var = (sq - total*total*(1.0f/(NT*NE))) * (1.0f/(NT*NE - 1));
    float stdv = sqrtf(fmaxf(var, 0.f));
    float ment = 0.f;
    #pragma unroll
    for (int e2 = 0; e2 < NE; ++e2) ment += out[ENT_OFF + e2];
    ment *= (1.0f/NE);
    out[AUX_OFF] = 0.5f*(stdv + ent) + 0.01f*ment;
  }
}

// ---------------- launch ------------------------------------------------------
extern "C" void kernel_launch(void* const* d_in, const int* in_sizes, int n_in,
                              void* d_out, int out_size, void* d_ws, size_t ws_size,
                              hipStream_t stream) {
  const float* h  = (const float*)d_in[0];
  const float* ce = (const float*)d_in[1];
  const float* gn = (const float*)d_in[2];
  const float* ca = (const float*)d_in[3];
  const float* fi = (const float*)d_in[4];
  const float* W1 = (const float*)d_in[5];
  const float* b1 = (const float*)d_in[6];
  const float* W2 = (const float*)d_in[7];
  const float* b2 = (const float*)d_in[8];
  float* out = (float*)d_out;
  char* ws = (char*)d_ws;
  // ws layout (bytes) — total 90,505,216 (Hbuf = [4][8192][1024] bf16 = 64MB)
  bf16*  w1t      = (bf16*)(ws);                 // [E][DH][DIN] bf16 (imp-folded): 10,485,760
  bf16*  w2t      = (bf16*)(ws + 10485760);      // [E][DOUT][DH] bf16: 2,097,152
  bf16*  xbuf     = (bf16*)(ws + 12582912);      // [8192][640] bf16: 10,485,760
  float* ew       = (float*)(ws + 23097344);     // [B][T][E]: 262,144
  bf16*  Hbuf     = (bf16*)(ws + 23396352);      // [4][8192][1024] bf16: 67,108,864

  k_prep<<<dim3(6153), dim3(256), 0, stream>>>(h, ce, gn, ca, fi, W1, W2,
                                               w1t, w2t, xbuf, ew, out);
  k_g1<<<dim3(1024), dim3(512), 0, stream>>>(xbuf, w1t, b1, Hbuf, 0);
  k_g2<<<dim3(512), dim3(256), 0, stream>>>(Hbuf, w2t, b2, ew, out, 0);
  k_g1<<<dim3(1024), dim3(512), 0, stream>>>(xbuf, w1t, b1, Hbuf, 4);
  k_g2<<<dim3(512), dim3(256), 0, stream>>>(Hbuf, w2t, b2, ew, out, 4);
  k_tail<<<dim3(1), dim3(1024), 0, stream>>>(ew, out);
}

// Round 18
// 187.456 us; speedup vs baseline: 3.0526x; 3.0526x over previous
//
#include <hip/hip_runtime.h>
#include <math.h>

#define DIN 640
#define DH 1024
#define DOUT 128
#define CODEDIM 256
#define NE 8
#define NB 8
#define NT 1024
#define NTOK 8192
#define TAU_INV 10.0f
#define FEPS 1e-8f

// out layout: full_output[8*1024*1024], aux[1], div[1], ent[8], mean[8], std[8]
#define AUX_OFF  8388608
#define DIV_OFF  8388609
#define ENT_OFF  8388610
#define MEAN_OFF 8388618
#define STD_OFF  8388626

typedef __bf16 bf16;
typedef bf16 bf16x8 __attribute__((ext_vector_type(8)));
typedef float f32x4 __attribute__((ext_vector_type(4)));

__device__ __forceinline__ float gelu(float x) {
  return 0.5f * x * (1.0f + erff(x * 0.70710678118654752f));
}

#define BAR() do { asm volatile("" ::: "memory"); __builtin_amdgcn_s_barrier(); asm volatile("" ::: "memory"); } while(0)
#define VMCNT6 asm volatile("s_waitcnt vmcnt(6)" ::: "memory")
#define VMCNT0 asm volatile("s_waitcnt vmcnt(0)" ::: "memory")

// async global->LDS, 16B/lane; LDS dest is wave-uniform base (HW adds lane*16);
// global source IS per-lane (pre-swizzled-global pattern, r5/r11/r12-proven).
__device__ __forceinline__ void gload16(const void* g, void* l) {
  __builtin_amdgcn_global_load_lds(
      (const __attribute__((address_space(1))) unsigned int*)g,
      (__attribute__((address_space(3))) unsigned int*)l, 16, 0, 0);
}

// ---------------- block reduction helpers (blockDim multiple of 64) ----------
__device__ __forceinline__ float blk_sum(float v, float* sb) {
  #pragma unroll
  for (int o = 32; o > 0; o >>= 1) v += __shfl_down(v, o, 64);
  __syncthreads();
  if ((threadIdx.x & 63) == 0) sb[threadIdx.x >> 6] = v;
  __syncthreads();
  float tot = 0.f;
  int nw = blockDim.x >> 6;
  for (int i = 0; i < nw; ++i) tot += sb[i];
  return tot;
}

__device__ __forceinline__ float blk_max(float v, float* sb) {
  #pragma unroll
  for (int o = 32; o > 0; o >>= 1) v = fmaxf(v, __shfl_down(v, o, 64));
  __syncthreads();
  if ((threadIdx.x & 63) == 0) sb[threadIdx.x >> 6] = v;
  __syncthreads();
  float m = -3.0e38f;
  int nw = blockDim.x >> 6;
  for (int i = 0; i < nw; ++i) m = fmaxf(m, sb[i]);
  return m;
}

// ================== fused prep: 6 roles in one launch (r13-proven) ===========
__global__ __launch_bounds__(256)
void k_prep(const float* __restrict__ h, const float* __restrict__ ce,
            const float* __restrict__ gn, const float* __restrict__ ca,
            const float* __restrict__ fi, const float* __restrict__ W1,
            const float* __restrict__ W2,
            bf16* __restrict__ w1t, bf16* __restrict__ w2t,
            bf16* __restrict__ xb, float* __restrict__ ew,
            float* __restrict__ out) {
  const int bid = blockIdx.x;
  const int tid = threadIdx.x;
  if (bid < 1280) {
    // ---- role A: W1[e][640][1024] -> w1t[e][1024][640]*imp, imp inline ----
    __shared__ float tile[64][65];
    __shared__ float sb[8];
    __shared__ float red[2];
    int c0 = (bid & 15) * 64;
    int r0 = ((bid >> 4) % 10) * 64;
    int ee = bid / 160;
    const float* s = W1 + (size_t)ee*DIN*DH;
    bf16* d = w1t + (size_t)ee*DH*DIN;
    int i2v = tid + 512;
    float v0 = fi[ee*DIN + tid] * 2.0f;
    float v1 = fi[ee*DIN + tid + 256] * 2.0f;
    float v2 = (i2v < DIN) ? fi[ee*DIN + i2v] * 2.0f : -3.0e38f;
    float m = blk_max(fmaxf(v0, fmaxf(v1, v2)), sb);
    float se = expf(v0 - m) + expf(v1 - m) + ((i2v < DIN) ? expf(v2 - m) : 0.f);
    float ssum = blk_sum(se, sb);
    if (tid == 0) { red[0] = m; red[1] = 1.0f / ssum; }
    int tx = tid & 63, ty = tid >> 6;
    #pragma unroll
    for (int p = 0; p < 16; ++p) {
      int r = p*4 + ty;
      tile[r][tx] = s[(size_t)(r0 + r)*DH + c0 + tx];
    }
    __syncthreads();
    float sc = expf(fi[ee*DIN + r0 + tx]*2.0f - red[0]) * red[1];
    #pragma unroll
    for (int p = 0; p < 16; ++p) {
      int cr = p*4 + ty;
      d[(size_t)(c0 + cr)*DIN + r0 + tx] = (bf16)(tile[tx][cr] * sc);
    }
  } else if (bid < 1536) {
    // ---- role B: W2[e][1024][128] -> w2t[e][128][1024] ----
    __shared__ float tile[64][65];
    int c = bid - 1280;
    int c0 = (c & 1) * 64;
    int r0 = ((c >> 1) & 15) * 64;
    int ee = c >> 5;
    const float* s = W2 + (size_t)ee*DH*DOUT;
    bf16* d = w2t + (size_t)ee*DOUT*DH;
    int tx = tid & 63, ty = tid >> 6;
    #pragma unroll
    for (int p = 0; p < 16; ++p) {
      int r = p*4 + ty;
      tile[r][tx] = s[(size_t)(r0 + r)*DOUT + c0 + tx];
    }
    __syncthreads();
    #pragma unroll
    for (int p = 0; p < 16; ++p) {
      int cr = p*4 + ty;
      d[(size_t)(c0 + cr)*DH + r0 + tx] = (bf16)tile[tx][cr];
    }
  } else if (bid < 4096) {
    // ---- role C: h f32 -> bf16 ----
    size_t i = (size_t)(bid - 1536)*256 + tid;
    const float4* p = (const float4*)(h + i*8);
    float4 u0 = p[0], u1 = p[1];
    bf16x8 o;
    o[0]=(bf16)u0.x; o[1]=(bf16)u0.y; o[2]=(bf16)u0.z; o[3]=(bf16)u0.w;
    o[4]=(bf16)u1.x; o[5]=(bf16)u1.y; o[6]=(bf16)u1.z; o[7]=(bf16)u1.w;
    *(bf16x8*)(xb + i*8) = o;
  } else if (bid < 6144) {
    // ---- role D: router, anchors normalized inline ----
    __shared__ float anc[NE*CODEDIM];
    __shared__ float sd[256];
    __shared__ float invn[8];
    int c = bid - 4096;
    for (int i = tid; i < NE*CODEDIM; i += 256) anc[i] = ca[i];
    __syncthreads();
    {
      int e8 = tid >> 5, base = e8*CODEDIM + (tid & 31)*8;
      float ps = 0.f;
      #pragma unroll
      for (int j = 0; j < 8; ++j) { float v = anc[base + j]; ps += v*v; }
      sd[tid] = ps;
    }
    __syncthreads();
    if (tid < 8) {
      float s2 = 0.f;
      for (int j = 0; j < 32; ++j) s2 += sd[tid*32 + j];
      invn[tid] = 1.0f / fmaxf(sqrtf(s2), 1e-12f);
    }
    __syncthreads();
    int wv = tid >> 6, lane = tid & 63;
    int token = c*4 + wv;
    float4 x = *(const float4*)(ce + (size_t)token*CODEDIM + lane*4);
    float ss = x.x*x.x + x.y*x.y + x.z*x.z + x.w*x.w;
    #pragma unroll
    for (int o = 1; o < 64; o <<= 1) ss += __shfl_xor(ss, o, 64);
    float invx = 1.0f / fmaxf(sqrtf(ss), 1e-12f);
    const float* g = gn + (size_t)token*NE;
    float z[8];
    float m = -3.0e38f;
    #pragma unroll
    for (int e2 = 0; e2 < NE; ++e2) {
      const float* a = anc + e2*CODEDIM + lane*4;
      float d = x.x*a[0] + x.y*a[1] + x.z*a[2] + x.w*a[3];
      #pragma unroll
      for (int o = 1; o < 64; o <<= 1) d += __shfl_xor(d, o, 64);
      z[e2] = (d * invx * invn[e2] + g[e2]) * TAU_INV;
      m = fmaxf(m, z[e2]);
    }
    float ssum = 0.f;
    float pz[8];
    #pragma unroll
    for (int e2 = 0; e2 < NE; ++e2) { pz[e2] = expf(z[e2] - m); ssum += pz[e2]; }
    float num = 0.f;
    #pragma unroll
    for (int e2 = 0; e2 < NE; ++e2) num = (lane == e2) ? pz[e2] : num;
    if (lane < NE) ew[(size_t)token*NE + lane] = num / ssum;
  } else if (bid < 6152) {
    // ---- role E: importance stats (ENT/MEAN/STD) ----
    __shared__ float sb[8];
    int e = bid - 6144;
    int d2v = tid + 512;
    float v0 = fi[e*DIN + tid] * 2.0f;
    float v1 = fi[e*DIN + tid + 256] * 2.0f;
    float v2 = (d2v < DIN) ? fi[e*DIN + d2v] * 2.0f : -3.0e38f;
    float m = blk_max(fmaxf(v0, fmaxf(v1, v2)), sb);
    float e0 = expf(v0 - m), e1 = expf(v1 - m);
    float e2 = (d2v < DIN) ? expf(v2 - m) : 0.f;
    float s = blk_sum(e0 + e1 + e2, sb);
    float inv = 1.0f / s;
    float p0 = e0*inv, p1 = e1*inv, p2 = e2*inv;
    float ok2 = (d2v < DIN) ? 1.f : 0.f;
    float sp  = p0 + p1 + ok2*p2;
    float sp2 = p0*p0 + p1*p1 + ok2*p2*p2;
    float sent = p0*logf(p0 + FEPS) + p1*logf(p1 + FEPS) + ok2*p2*logf(p2 + FEPS);
    sp   = blk_sum(sp, sb);
    sp2  = blk_sum(sp2, sb);
    sent = blk_sum(sent, sb);
    if (tid == 0) {
      out[ENT_OFF + e]  = -sent;
      out[MEAN_OFF + e] = sp * (1.0f/DIN);
      float var = (sp2 - sp*sp*(1.0f/DIN)) * (1.0f/(DIN-1));
      out[STD_OFF + e]  = sqrtf(fmaxf(var, 0.f));
    }
  } else {
    // ---- role F: diversity loss ----
    __shared__ float sd[256];
    int p = tid >> 2, q = tid & 3;
    int i = p >> 3, j = p & 7;
    float dot = 0.f;
    for (int d = q*160; d < q*160 + 160; ++d) dot += fi[i*DIN + d] * fi[j*DIN + d];
    sd[tid] = dot;
    __syncthreads();
    if (tid < 64) {
      float s = sd[tid*4] + sd[tid*4+1] + sd[tid*4+2] + sd[tid*4+3];
      int ii = tid >> 3, jj = tid & 7;
      float val = (ii != jj) ? s*s : 0.f;
      #pragma unroll
      for (int o = 32; o > 0; o >>= 1) val += __shfl_down(val, o, 64);
      if (tid == 0) out[DIV_OFF] = val * (1.0f/56.0f);
    }
  }
}

// ================== GEMM1: H = gelu(X @ W1 + b1), bf16 out ===================
// r12/r13-proven (FROZEN — empirical optimum of 7 structural variants):
// 128x128 tile, BK=64, single-buffered 34.8KB LDS, 256 thr -> 3 blocks/CU =
// 12 waves/CU at VGPR 64+64 (cap 170, no spill). Swizzle slot^row&7;
// inverse-swizzled per-lane global src + linear gload dest (T21).
#define G1_LDS 34816
__global__ __launch_bounds__(256, 3)
void k_g1(const bf16* __restrict__ xb, const bf16* __restrict__ w1t,
          const float* __restrict__ b1, bf16* __restrict__ Hb, int ebase) {
  __shared__ __align__(16) char L[G1_LDS];
  const int bid = blockIdx.x;
  const int el = bid & 3, e = ebase + el;
  const int nt = (bid >> 2) & 7, mt = bid >> 5;
  const int M0 = mt * 128, N0 = nt * 128;
  const int tid = threadIdx.x;
  const int lane = tid & 63, w = tid >> 6;
  const int l15 = lane & 15, g4 = lane >> 4;
  const int wr = w >> 1, wc = w & 1;

  const char* gAsrc[4];
  const char* gBsrc[4];
  #pragma unroll
  for (int j = 0; j < 4; ++j) {
    unsigned p = (unsigned)((w*4 + j)*1024 + lane*16);
    unsigned q = p ^ (((p >> 7) & 7u) << 4);
    gAsrc[j] = (const char*)xb + (size_t)(M0 + (int)(q >> 7))*(DIN*2) + (q & 127u);
    gBsrc[j] = (const char*)w1t + (size_t)(e*DH + N0 + (int)(q >> 7))*(DIN*2) + (q & 127u);
  }

  unsigned afOff[4][2], bfOff[4][2];
  #pragma unroll
  for (int mi = 0; mi < 4; ++mi)
    #pragma unroll
    for (int kk = 0; kk < 2; ++kk) {
      int row = wr*64 + mi*16 + l15;
      int slot = kk*4 + g4;
      afOff[mi][kk] = (unsigned)(row*128 + ((slot ^ (row & 7)) << 4));
    }
  #pragma unroll
  for (int ni = 0; ni < 4; ++ni)
    #pragma unroll
    for (int kk = 0; kk < 2; ++kk) {
      int row = wc*64 + ni*16 + l15;
      int slot = kk*4 + g4;
      bfOff[ni][kk] = (unsigned)(16384 + row*128 + ((slot ^ (row & 7)) << 4));
    }

  f32x4 acc[4][4] = {};
  for (int t = 0; t < 10; ++t) {
    if (t) BAR();
    size_t ko = (size_t)t * 128;
    #pragma unroll
    for (int j = 0; j < 4; ++j) {
      gload16(gAsrc[j] + ko, L + (w*4 + j)*1024);
      gload16(gBsrc[j] + ko, L + 16384 + (w*4 + j)*1024);
    }
    VMCNT0;
    BAR();
    #pragma unroll
    for (int kk = 0; kk < 2; ++kk) {
      bf16x8 af[4], bfr[4];
      #pragma unroll
      for (int mi = 0; mi < 4; ++mi) af[mi] = *(const bf16x8*)(L + afOff[mi][kk]);
      #pragma unroll
      for (int ni = 0; ni < 4; ++ni) bfr[ni] = *(const bf16x8*)(L + bfOff[ni][kk]);
      #pragma unroll
      for (int mi = 0; mi < 4; ++mi)
        #pragma unroll
        for (int ni = 0; ni < 4; ++ni)
          acc[mi][ni] = __builtin_amdgcn_mfma_f32_16x16x32_bf16(
              af[mi], bfr[ni], acc[mi][ni], 0, 0, 0);
    }
  }
  BAR();
  float b1v[4];
  #pragma unroll
  for (int ni = 0; ni < 4; ++ni)
    b1v[ni] = b1[e*DH + N0 + wc*64 + ni*16 + l15];
  #pragma unroll
  for (int mi = 0; mi < 4; ++mi)
    #pragma unroll
    for (int ni = 0; ni < 4; ++ni)
      #pragma unroll
      for (int r = 0; r < 4; ++r) {
        float v = gelu(acc[mi][ni][r] + b1v[ni]);
        int row = wr*64 + mi*16 + g4*4 + r;
        int col = wc*64 + ni*16 + l15;
        *(bf16*)(L + row*272 + col*2) = (bf16)v;
      }
  __syncthreads();
  #pragma unroll
  for (int j = 0; j < 8; ++j) {
    int c = j*256 + tid;
    int row = c >> 4, slot = c & 15;
    bf16x8 v = *(const bf16x8*)(L + row*272 + slot*16);
    *(bf16x8*)((char*)Hb + (size_t)(el*NTOK + M0 + row)*(DH*2) + (size_t)N0*2 + slot*16) = v;
  }
}

// ================== GEMM2: out = (H @ W2 + b2) * gate, f32 ===================
// r11-proven (FROZEN): 64x128 tile, BK=64, dbuf, counted vmcnt(6).
__global__ __launch_bounds__(256, 3)
void k_g2(const bf16* __restrict__ Hb, const bf16* __restrict__ w2t,
          const float* __restrict__ b2, const float* __restrict__ ew,
          float* __restrict__ out, int ebase) {
  __shared__ __align__(16) char L[49152];
  const int bid = blockIdx.x;
  const int el = bid & 3, e = ebase + el;
  const int mt = bid >> 2;
  const int M0 = mt * 64;
  const int tid = threadIdx.x;
  const int lane = tid & 63, w = tid >> 6;
  const int l15 = lane & 15, g4 = lane >> 4;
  const int nb = w * 32;

  const char* gAsrc[2];
  #pragma unroll
  for (int j = 0; j < 2; ++j) {
    unsigned p = (unsigned)((w*2 + j)*1024 + lane*16);
    unsigned q = p ^ (((p >> 7) & 7u) << 4);
    gAsrc[j] = (const char*)Hb + (size_t)(el*NTOK + M0 + (int)(q >> 7))*(DH*2) + (q & 127u);
  }
  const char* gBsrc[4];
  #pragma unroll
  for (int j = 0; j < 4; ++j) {
    unsigned p = (unsigned)((w*4 + j)*1024 + lane*16);
    unsigned q = p ^ (((p >> 7) & 7u) << 4);
    gBsrc[j] = (const char*)w2t + (size_t)(e*DOUT + (int)(q >> 7))*(DH*2) + (q & 127u);
  }
  auto STAGE = [&](int buf, int t) {
    size_t ko = (size_t)t * 128;
    #pragma unroll
    for (int j = 0; j < 2; ++j)
      gload16(gAsrc[j] + ko, L + buf*8192 + (w*2 + j)*1024);
    #pragma unroll
    for (int j = 0; j < 4; ++j)
      gload16(gBsrc[j] + ko, L + 16384 + buf*16384 + (w*4 + j)*1024);
  };

  unsigned afOff[4][2], bfOff[2][2];
  #pragma unroll
  for (int mi = 0; mi < 4; ++mi)
    #pragma unroll
    for (int kk = 0; kk < 2; ++kk) {
      int row = mi*16 + l15;
      int slot = kk*4 + g4;
      afOff[mi][kk] = (unsigned)(row*128 + ((slot ^ (row & 7)) << 4));
    }
  #pragma unroll
  for (int ni = 0; ni < 2; ++ni)
    #pragma unroll
    for (int kk = 0; kk < 2; ++kk) {
      int row = nb + ni*16 + l15;
      int slot = kk*4 + g4;
      bfOff[ni][kk] = (unsigned)(row*128 + ((slot ^ (row & 7)) << 4));
    }

  f32x4 acc[4][2] = {};
  STAGE(0, 0);
  for (int t = 0; t < 16; ++t) {
    int buf = t & 1;
    if (t < 15) { STAGE(buf ^ 1, t + 1); VMCNT6; } else { VMCNT0; }
    BAR();
    const char* Ab = L + buf*8192;
    const char* Bb = L + 16384 + buf*16384;
    #pragma unroll
    for (int kk = 0; kk < 2; ++kk) {
      bf16x8 af[4], bfr[2];
      #pragma unroll
      for (int mi = 0; mi < 4; ++mi) af[mi] = *(const bf16x8*)(Ab + afOff[mi][kk]);
      #pragma unroll
      for (int ni = 0; ni < 2; ++ni) bfr[ni] = *(const bf16x8*)(Bb + bfOff[ni][kk]);
      #pragma unroll
      for (int mi = 0; mi < 4; ++mi)
        #pragma unroll
        for (int ni = 0; ni < 2; ++ni)
          acc[mi][ni] = __builtin_amdgcn_mfma_f32_16x16x32_bf16(
              af[mi], bfr[ni], acc[mi][ni], 0, 0, 0);
    }
    BAR();
  }
  float b2v[2];
  #pragma unroll
  for (int ni = 0; ni < 2; ++ni)
    b2v[ni] = b2[e*DOUT + nb + ni*16 + l15];
  float gt[4][4];
  #pragma unroll
  for (int mi = 0; mi < 4; ++mi)
    #pragma unroll
    for (int r = 0; r < 4; ++r)
      gt[mi][r] = ew[(size_t)(M0 + mi*16 + g4*4 + r)*NE + e];
  #pragma unroll
  for (int mi = 0; mi < 4; ++mi)
    #pragma unroll
    for (int ni = 0; ni < 2; ++ni)
      #pragma unroll
      for (int r = 0; r < 4; ++r) {
        int tok = M0 + mi*16 + g4*4 + r;
        int o = nb + ni*16 + l15;
        out[(size_t)tok*(NE*DOUT) + e*DOUT + o] = (acc[mi][ni][r] + b2v[ni]) * gt[mi][r];
      }
}

// ---------------- expert counts + partial sums --------------------------------
__global__ void k_counts(const float* __restrict__ ew, float* __restrict__ counts,
                         float* __restrict__ partials) {
  __shared__ float sb[4];
  int g2 = blockIdx.x*256 + threadIdx.x;
  float c = 0.f;
  #pragma unroll
  for (int b = 0; b < NB; ++b) c += ew[b*(NT*NE) + g2];
  counts[g2] = c;
  float tot = blk_sum(c, sb);
  if (threadIdx.x == 0) partials[blockIdx.x] = tot;
}

// ---------------- aux loss ----------------------------------------------------
__global__ void k_aux(const float* __restrict__ counts, const float* __restrict__ partials,
                      float* __restrict__ out) {
  __shared__ float sb[4];
  int tid = threadIdx.x;
  float pv = (tid < 32) ? partials[tid] : 0.f;
  float total = blk_sum(pv, sb);
  float invt = 1.0f / (total + FEPS);
  float sq = 0.f, ent = 0.f;
  for (int i2 = tid; i2 < NT*NE; i2 += 256) {
    float c = counts[i2];
    sq += c*c;
    float ld = c * invt;
    ent -= ld * logf(ld + FEPS);
  }
  sq = blk_sum(sq, sb);
  ent = blk_sum(ent, sb);
  if (tid == 0) {
    float var = (sq - total*total*(1.0f/(NT*NE))) * (1.0f/(NT*NE - 1));
    float stdv = sqrtf(fmaxf(var, 0.f));
    float ment = 0.f;
    #pragma unroll
    for (int e2 = 0; e2 < NE; ++e2) ment += out[ENT_OFF + e2];
    ment *= (1.0f/NE);
    out[AUX_OFF] = 0.5f*(stdv + ent) + 0.01f*ment;
  }
}

// ---------------- launch ------------------------------------------------------
extern "C" void kernel_launch(void* const* d_in, const int* in_sizes, int n_in,
                              void* d_out, int out_size, void* d_ws, size_t ws_size,
                              hipStream_t stream) {
  const float* h  = (const float*)d_in[0];
  const float* ce = (const float*)d_in[1];
  const float* gn = (const float*)d_in[2];
  const float* ca = (const float*)d_in[3];
  const float* fi = (const float*)d_in[4];
  const float* W1 = (const float*)d_in[5];
  const float* b1 = (const float*)d_in[6];
  const float* W2 = (const float*)d_in[7];
  const float* b2 = (const float*)d_in[8];
  float* out = (float*)d_out;
  char* ws = (char*)d_ws;
  // ws layout (bytes) — total 90,505,216 (Hbuf = [4][8192][1024] bf16 = 64MB)
  bf16*  w1t      = (bf16*)(ws);                 // [E][DH][DIN] bf16 (imp-folded): 10,485,760
  bf16*  w2t      = (bf16*)(ws + 10485760);      // [E][DOUT][DH] bf16: 2,097,152
  bf16*  xbuf     = (bf16*)(ws + 12582912);      // [8192][640] bf16: 10,485,760
  float* ew       = (float*)(ws + 23097344);     // [B][T][E]: 262,144
  float* counts   = (float*)(ws + 23359488);     // [T*E]: 32,768
  float* partials = (float*)(ws + 23392256);     // [32]: 128
  bf16*  Hbuf     = (bf16*)(ws + 23396352);      // [4][8192][1024] bf16: 67,108,864

  k_prep<<<dim3(6153), dim3(256), 0, stream>>>(h, ce, gn, ca, fi, W1, W2,
                                               w1t, w2t, xbuf, ew, out);
  k_g1<<<dim3(2048), dim3(256), 0, stream>>>(xbuf, w1t, b1, Hbuf, 0);
  k_g2<<<dim3(512), dim3(256), 0, stream>>>(Hbuf, w2t, b2, ew, out, 0);
  k_g1<<<dim3(2048), dim3(256), 0, stream>>>(xbuf, w1t, b1, Hbuf, 4);
  k_g2<<<dim3(512), dim3(256), 0, stream>>>(Hbuf, w2t, b2, ew, out, 4);
  k_counts<<<dim3(32), dim3(256), 0, stream>>>(ew, counts, partials);
  k_aux<<<dim3(1), dim3(256), 0, stream>>>(counts, partials, out);
}